// Round 1
// baseline (370.125 us; speedup 1.0000x reference)
//
#include <hip/hip_runtime.h>
#include <hip/hip_bf16.h>
#include <stdint.h>

#define B_ROWS 32768
#define HID    2048
#define K_DIM  2048

#define BM 128
#define BN 128
#define BK 64   // 2 MFMA k-steps (16x16x32) per staged tile; LDS = 2*16KB

typedef __bf16 bf16x8_t __attribute__((ext_vector_type(8)));
typedef float  f32x4_t  __attribute__((ext_vector_type(4)));

// tanh via v_exp + v_rcp: ~6 VALU ops, abs err ~1e-7 (negligible vs bf16 budget).
// Saturates correctly: exp overflow -> +1, underflow -> -1.
__device__ __forceinline__ float fast_tanh(float x) {
    float e = __expf(2.0f * x);
    return 1.0f - 2.0f * __builtin_amdgcn_rcpf(e + 1.0f);
}

// async global->LDS, 16B/lane. LDS dest is wave-uniform base + lane*16.
// AS3 pointer recovered by truncating the flat address (LDS aperture is 2^32-aligned).
__device__ __forceinline__ void gl_lds16(const void* g, void* l) {
    __builtin_amdgcn_global_load_lds(
        (const __attribute__((address_space(1))) void*)(uintptr_t)g,
        (__attribute__((address_space(3))) void*)(uint32_t)(uintptr_t)l,
        16, 0, 0);
}

// ---------------- kernel 1: W2 [K,N] fp32 -> W2t [N,K] bf16 ----------------
__global__ __launch_bounds__(256) void transpose_w2_kernel(
    const float* __restrict__ W2, __bf16* __restrict__ W2t) {
    __shared__ float tile[32][33];           // +1 pad breaks bank conflicts
    const int n0 = blockIdx.x * 32;
    const int k0 = blockIdx.y * 32;
    const int tx = threadIdx.x;              // 0..31
    const int ty = threadIdx.y;              // 0..7
#pragma unroll
    for (int i = 0; i < 4; ++i) {
        int k = k0 + ty + i * 8;
        tile[ty + i * 8][tx] = W2[(size_t)k * HID + n0 + tx];   // coalesced in n
    }
    __syncthreads();
#pragma unroll
    for (int i = 0; i < 4; ++i) {
        int n = n0 + ty + i * 8;
        W2t[(size_t)n * K_DIM + k0 + tx] = (__bf16)tile[tx][ty + i * 8]; // coalesced in k
    }
}

// ------- kernel 2: layer1 (6-feature GEMV) -> h1 bf16; regressor; logit init -------
// block = 256 threads handles 8 batch rows; each thread owns 8 consecutive hidden cols
// so the W1 slice (40 floats after folding the two constant-1 features + b1) stays in regs.
__global__ __launch_bounds__(256) void layer1_kernel(
    const float* __restrict__ x,   const float* __restrict__ W1, const float* __restrict__ b1,
    const float* __restrict__ Wr1, const float* __restrict__ br1,
    const float* __restrict__ Wr2, const float* __restrict__ br2,
    const float* __restrict__ Wr3, const float* __restrict__ br3,
    const float* __restrict__ bc,
    __bf16* __restrict__ h1, float* __restrict__ out) {
    const int t  = threadIdx.x;
    const int n0 = t * 8;
    float w0[8], w1[8], w2[8], w3[8], wb[8];
#pragma unroll
    for (int j = 0; j < 8; ++j) {
        w0[j] = W1[0 * HID + n0 + j];
        w1[j] = W1[1 * HID + n0 + j];
        w2[j] = W1[2 * HID + n0 + j];
        w3[j] = W1[3 * HID + n0 + j];
        // qfeat[2]=qfeat[3]=1 always (cos(0) on padded wires) -> fold into bias
        wb[j] = W1[4 * HID + n0 + j] + W1[5 * HID + n0 + j] + b1[n0 + j];
    }
    const int brow0 = blockIdx.x * 8;
#pragma unroll
    for (int r = 0; r < 8; ++r) {
        const int b = brow0 + r;
        const float x0 = x[2 * b], x1 = x[2 * b + 1];
        const float c0 = cosf(x0);
        const float cc = c0 * cosf(x1);
        bf16x8_t v;
#pragma unroll
        for (int j = 0; j < 8; ++j) {
            float z = wb[j] + x0 * w0[j] + x1 * w1[j] + c0 * w2[j] + cc * w3[j];
            v[j] = (__bf16)fast_tanh(z);
        }
        *(bf16x8_t*)(h1 + (size_t)b * HID + n0) = v;   // 16B store
    }
    // tiny regressor + init logits with bc (d_out is poisoned before every launch)
    if (t < 8) {
        const int b = brow0 + t;
        const float x0 = x[2 * b], x1 = x[2 * b + 1];
        float r1[8];
#pragma unroll
        for (int j = 0; j < 8; ++j)
            r1[j] = fast_tanh(br1[j] + x0 * Wr1[j] + x1 * Wr1[8 + j]);
        float r2[4];
#pragma unroll
        for (int j = 0; j < 4; ++j) {
            float s = br2[j];
#pragma unroll
            for (int i = 0; i < 8; ++i) s += r1[i] * Wr2[i * 4 + j];
            r2[j] = fast_tanh(s);
        }
        float risk = br3[0];
#pragma unroll
        for (int i = 0; i < 4; ++i) risk += r2[i] * Wr3[i];
        out[B_ROWS + b] = risk;
        out[b]          = bc[0];
    }
}

// ------- kernel 3: h1[M,K]bf16 @ W2t[N,K]bf16 -> tanh(+b2) -> dot Wc -> atomic logits -------
// m97 structure: 128x128 tile, 4 waves, each wave 64x64 via 4x4 of mfma_f32_16x16x32_bf16.
// LDS chunk placement XOR-swizzled by row&7 so fragment ds_read_b128 is conflict-free
// (stride-128B rows otherwise put all 16 rows on banks 0..3 = 16-way conflict).
__global__ __launch_bounds__(256, 2) void gemm_kernel(
    const __bf16* __restrict__ A,   // h1  [32768, 2048]
    const __bf16* __restrict__ Bt,  // W2t [2048, 2048]
    const float* __restrict__ b2, const float* __restrict__ Wc,
    float* __restrict__ out) {
    __shared__ __align__(16) unsigned short sA[BM * BK];  // [row][64] bf16, no pad (gl_lds)
    __shared__ __align__(16) unsigned short sB[BN * BK];

    const int tid  = threadIdx.x;
    const int wave = tid >> 6;
    const int lane = tid & 63;
    const int bid  = blockIdx.x;
    const int m0 = (bid >> 4) * BM;   // 256 m-tiles; 16 consecutive blocks share the A tile (L2)
    const int n0 = (bid & 15) * BN;   // 16 n-tiles

    // staging: each wave issues 4 A-calls + 4 B-calls of 1KB (8 rows x 128B).
    // lane l -> row seg*8 + l/8, LDS slot l%8; global chunk = (l%8) ^ (l/8)  [swizzle]
    const char* aSrc[4]; const char* bSrc[4]; char* aDst[4]; char* bDst[4];
#pragma unroll
    for (int i = 0; i < 4; ++i) {
        int seg   = wave * 4 + i;
        int row   = seg * 8 + (lane >> 3);
        int chunk = (lane & 7) ^ (lane >> 3);
        aSrc[i] = (const char*)A  + (size_t)(m0 + row) * (K_DIM * 2) + chunk * 16;
        bSrc[i] = (const char*)Bt + (size_t)(n0 + row) * (K_DIM * 2) + chunk * 16;
        aDst[i] = (char*)sA + seg * 1024;
        bDst[i] = (char*)sB + seg * 1024;
    }

    f32x4_t acc[4][4] = {};
    const int mw   = (wave & 1) * 64;
    const int nw   = (wave >> 1) * 64;
    const int quad = lane >> 4;
    const int r16  = lane & 15;
    const int x7   = lane & 7;

    for (int kb = 0; kb < K_DIM * 2; kb += BK * 2) {
#pragma unroll
        for (int i = 0; i < 4; ++i) {
            gl_lds16(aSrc[i] + kb, aDst[i]);
            gl_lds16(bSrc[i] + kb, bDst[i]);
        }
        __syncthreads();
#pragma unroll
        for (int ks = 0; ks < 2; ++ks) {
            bf16x8_t af[4], bfr[4];
#pragma unroll
            for (int i = 0; i < 4; ++i) {
                int slot = (((ks * 4 + quad) ^ x7)) * 8;    // un-swizzle
                af[i]  = *(const bf16x8_t*)(sA + (mw + i * 16 + r16) * BK + slot);
                bfr[i] = *(const bf16x8_t*)(sB + (nw + i * 16 + r16) * BK + slot);
            }
#pragma unroll
            for (int mi = 0; mi < 4; ++mi)
#pragma unroll
                for (int ni = 0; ni < 4; ++ni)
                    acc[mi][ni] = __builtin_amdgcn_mfma_f32_16x16x32_bf16(
                        af[mi], bfr[ni], acc[mi][ni], 0, 0, 0);
        }
        __syncthreads();
    }

    // epilogue: h2 = tanh(acc + b2); logits += h2 . Wc  (h2 never hits memory)
    // C/D layout (m89/m91-verified): col = lane&15, row = quad*4 + reg
    float b2v[4], wcv[4];
#pragma unroll
    for (int ni = 0; ni < 4; ++ni) {
        int gn = n0 + nw + ni * 16 + r16;
        b2v[ni] = b2[gn];
        wcv[ni] = Wc[gn];
    }
#pragma unroll
    for (int mi = 0; mi < 4; ++mi) {
#pragma unroll
        for (int r = 0; r < 4; ++r) {
            int gm = m0 + mw + mi * 16 + quad * 4 + r;
            float rs = 0.f;
#pragma unroll
            for (int ni = 0; ni < 4; ++ni)
                rs += fast_tanh(acc[mi][ni][r] + b2v[ni]) * wcv[ni];
            rs += __shfl_xor(rs, 1);
            rs += __shfl_xor(rs, 2);
            rs += __shfl_xor(rs, 4);
            rs += __shfl_xor(rs, 8);   // 16-lane group = this wave's 64 cols for row gm
            if (r16 == 0) atomicAdd(&out[gm], rs);  // 32 atomics/row total
        }
    }
}

extern "C" void kernel_launch(void* const* d_in, const int* in_sizes, int n_in,
                              void* d_out, int out_size, void* d_ws, size_t ws_size,
                              hipStream_t stream) {
    const float* x   = (const float*)d_in[0];
    const float* W1  = (const float*)d_in[1];
    const float* b1  = (const float*)d_in[2];
    const float* W2  = (const float*)d_in[3];
    const float* b2  = (const float*)d_in[4];
    const float* Wc  = (const float*)d_in[5];
    const float* bc  = (const float*)d_in[6];
    const float* Wr1 = (const float*)d_in[7];
    const float* br1 = (const float*)d_in[8];
    const float* Wr2 = (const float*)d_in[9];
    const float* br2 = (const float*)d_in[10];
    const float* Wr3 = (const float*)d_in[11];
    const float* br3 = (const float*)d_in[12];
    float* out = (float*)d_out;

    // ws layout: [0,8MB) W2t bf16 [N,K]; [8MB, 8MB+128MB) h1 bf16 [B,H]
    __bf16* W2t = (__bf16*)d_ws;
    __bf16* h1  = (__bf16*)((char*)d_ws + (size_t)8 * 1024 * 1024);

    transpose_w2_kernel<<<dim3(HID / 32, K_DIM / 32), dim3(32, 8), 0, stream>>>(W2, W2t);
    layer1_kernel<<<B_ROWS / 8, 256, 0, stream>>>(x, W1, b1, Wr1, br1, Wr2, br2,
                                                  Wr3, br3, bc, h1, out);
    gemm_kernel<<<(B_ROWS / BM) * (HID / BN), 256, 0, stream>>>(h1, W2t, b2, Wc, out);
}